// Round 7
// baseline (317.176 us; speedup 1.0000x reference)
//
#include <hip/hip_runtime.h>
#include <stdint.h>

// BilinearScorer: out[n,r] = sum_{h,k} pred[n,h] U[h,r,k] args[n,k] + bias1[r,:].args[n,:] + bias2[r]
// n=4096, h=k=512, R=64.  137.4 GFLOP fp32-equivalent.
// R12 = MFMA shape switch 16x16x32 -> 32x32x16 (single variable).
// R11 post-mortem: total 275.6 (launch model ~23us/dispatch confirmed); main 175us =
// 785 TF-equiv = m97-structure ceiling for short-K. 32x32 matrix pipe is 17% more
// efficient (2495 vs 2075 TF ubench): per K-step busy 155->129 cyc. Staging/swizzle/
// grid/epilogue-structure unchanged. C/D layout: col=lane&31, row=(reg&3)+8*(reg>>2)
// +4*(lane>>5) (m74/m101). A/B: row=lane&31, k=(lane>>5)*8+j (16x16-verified pattern
// generalized). n-reduce now over 32 lanes (shfl_xor 1..16).
// NOTE: MfmaUtil is EXPECTED to drop (~30%) even if time improves — fewer busy cycles.
// R10 lesson: no per-block device-scope fences. R5: (256,3) unified reg cap.

#define HID   512
#define ROLES 64
#define NTOK  4096
#define BM    128
#define BN    128
#define BK    64

typedef __attribute__((ext_vector_type(8)))  _Float16 f16x8;   // MFMA A/B: 4 VGPRs
typedef __attribute__((ext_vector_type(4)))  _Float16 f16x4;
typedef __attribute__((ext_vector_type(16))) float    f32x16;  // 32x32 C/D: 16 regs

__device__ __forceinline__ void async16(const void* g, void* l) {
  // global -> LDS direct copy, 16B/lane. LDS dest is wave-uniform base + lane*16;
  // per-lane SOURCE address is free (implements the store-side swizzle).
  __builtin_amdgcn_global_load_lds(
      (const __attribute__((address_space(1))) uint32_t*)g,
      (__attribute__((address_space(3))) uint32_t*)l, 16, 0, 0);
}

// ---- fused prep: blocks [0,2048) transpose U; [2048,4096) convert pred ----
__global__ __launch_bounds__(256) void prep_fused(
    const float* __restrict__ pred_in, _Float16* __restrict__ predf,
    const float* __restrict__ U, _Float16* __restrict__ ut) {
  __shared__ float tile[128][65];                // pad 65: col-reads 4-way max
  const int bx = blockIdx.x;
  const int t  = threadIdx.x;

  if (bx >= 2048) {                              // ---- cvt_pred path ----
    const int idx = (bx - 2048) * 256 + t;       // 2048 blocks x 256 x float4
    const float4 v = ((const float4*)pred_in)[idx];
    f16x4 o;
    o[0] = (_Float16)v.x; o[1] = (_Float16)v.y;
    o[2] = (_Float16)v.z; o[3] = (_Float16)v.w;
    ((f16x4*)predf)[idx] = o;
    return;
  }

  // ---- cvt_u path: grid-flattened (kb 8, hb 4, r 64) ----
  const int kb = bx & 7, hb = (bx >> 3) & 3, r = bx >> 5;
  const int h0 = hb * 128, k0 = kb * 64;
  const int rr = t >> 4, c4 = (t & 15) * 4;
#pragma unroll
  for (int pass = 0; pass < 8; pass++) {
    const int row = pass * 16 + rr;
    const float4 v = *(const float4*)(U + ((size_t)(h0 + row) * ROLES + r) * HID + k0 + c4);
    tile[row][c4 + 0] = v.x; tile[row][c4 + 1] = v.y;
    tile[row][c4 + 2] = v.z; tile[row][c4 + 3] = v.w;
  }
  __syncthreads();
  const int kr = t >> 4, hc = (t & 15) * 8;
#pragma unroll
  for (int pass = 0; pass < 4; pass++) {
    const int k = pass * 16 + kr;
    alignas(16) _Float16 hbuf[8];
#pragma unroll
    for (int j = 0; j < 8; j++) hbuf[j] = (_Float16)tile[hc + j][k];
    *(uint4*)(ut + ((size_t)r * HID + k0 + k) * HID + h0 + hc) = *(const uint4*)hbuf;
  }
}

// ---- main fused GEMM (32x32x16 MFMA) --------------------------------------
__global__ __launch_bounds__(256, 3) void bilinear_mfma(
    const _Float16* __restrict__ predf, const _Float16* __restrict__ utf,
    const float* __restrict__ args, const float* __restrict__ bias1,
    float* __restrict__ part) {
  __shared__ _Float16 sA[BM * BK];               // 16 KB
  __shared__ _Float16 sB[BN * BK];               // 16 KB

  const int nblk = blockIdx.x, mblk = blockIdx.y, r = blockIdx.z;
  const int m0 = mblk * BM, n0 = nblk * BN;
  const int tid  = threadIdx.x;
  const int wave = tid >> 6, lane = tid & 63;
  const int colq = lane & 31, hi = lane >> 5;    // 32x32 operand mapping
  const int wm = (wave & 1) * 64, wn = (wave >> 1) * 64;

  // staging: tile = 128 rows x 64 f16 (128B/row) = 1024 x 16B chunks, 4 calls.
  // XOR swizzle: LDS slot s of row i holds global chunk (s ^ (i&7)); every 8
  // consecutive lanes cover all 8 bank groups (R2/R3-verified: 0 conflicts).
  const int i_loc = tid >> 3;                    // row 0..31 within call (+32/call)
  const int ko    = ((tid & 7) ^ (i_loc & 7)) * 8;
  const size_t offA = (size_t)(m0 + i_loc) * HID + ko;
  const size_t offB = ((size_t)r * HID + n0 + i_loc) * HID + ko;
  const int ldsW = wave * 512;                   // f16 elems (64 chunks/wave/call)

  // reader: frag row = base + (lane&31), base ≡ 0 mod 8 -> row&7 = lane&7.
  // chunk for k-quarter kq = kq*2 + hi; swizzled slot = chunk ^ (lane&7).
  // bank check: each 16-lane quarter-wave = 8 distinct slots x 2 rows = 2-way (free).
  const int rowA0 = (wm + colq) * BK, rowA1 = rowA0 + 32 * BK;
  const int rowB0 = (wn + colq) * BK, rowB1 = rowB0 + 32 * BK;
  int slq[4];
#pragma unroll
  for (int kq = 0; kq < 4; kq++) slq[kq] = ((kq * 2 + hi) ^ (lane & 7)) * 8;

  f32x16 acc00, acc01, acc10, acc11;
#pragma unroll
  for (int j = 0; j < 16; j++) { acc00[j] = 0.f; acc01[j] = 0.f; acc10[j] = 0.f; acc11[j] = 0.f; }

  for (int k0 = 0; k0 < HID; k0 += BK) {
#pragma unroll
    for (int c = 0; c < 4; c++) {
      async16(predf + offA + (size_t)(c * 32) * HID + k0, sA + c * 2048 + ldsW);
      async16(utf   + offB + (size_t)(c * 32) * HID + k0, sB + c * 2048 + ldsW);
    }
    __syncthreads();                             // drains vmcnt (staging done)

#pragma unroll
    for (int kq = 0; kq < 4; kq++) {             // k in [k0+16*kq, k0+16*kq+16)
      const int sl = slq[kq];
      const f16x8 a0 = *(const f16x8*)(sA + rowA0 + sl);
      const f16x8 a1 = *(const f16x8*)(sA + rowA1 + sl);
      const f16x8 b0 = *(const f16x8*)(sB + rowB0 + sl);
      const f16x8 b1 = *(const f16x8*)(sB + rowB1 + sl);
      acc00 = __builtin_amdgcn_mfma_f32_32x32x16_f16(a0, b0, acc00, 0, 0, 0);
      acc01 = __builtin_amdgcn_mfma_f32_32x32x16_f16(a0, b1, acc01, 0, 0, 0);
      acc10 = __builtin_amdgcn_mfma_f32_32x32x16_f16(a1, b0, acc10, 0, 0, 0);
      acc11 = __builtin_amdgcn_mfma_f32_32x32x16_f16(a1, b1, acc11, 0, 0, 0);
    }
    __syncthreads();
  }

  // epilogue: s over this wave's 64 n-cols of (T + bias1)*args, reduced over the
  // 32-lane col group (shfl_xor 1..16; valid at colq==0 -> lanes 0 and 32).
  // C/D: col = lane&31, row = (i&3) + 8*(i>>2) + 4*hi  (m74/m101).
  const float b1v0 = bias1[r * HID + n0 + wn + colq];
  const float b1v1 = bias1[r * HID + n0 + wn + 32 + colq];

  float sval[2][16];
  auto epi = [&](int MT, const f32x16& A0, const f32x16& A1, float* sv) {
#pragma unroll
    for (int i = 0; i < 16; i++) {
      const int m = m0 + wm + MT * 32 + (i & 3) + 8 * (i >> 2) + 4 * hi;
      const float* arow = args + (size_t)m * HID + n0 + wn + colq;
      float s = (A0[i] + b1v0) * arow[0] + (A1[i] + b1v1) * arow[32];
      s += __shfl_xor(s, 1);
      s += __shfl_xor(s, 2);
      s += __shfl_xor(s, 4);
      s += __shfl_xor(s, 8);
      s += __shfl_xor(s, 16);
      sv[i] = s;
    }
  };
  epi(0, acc00, acc01, sval[0]);
  epi(1, acc10, acc11, sval[1]);

  // cross-wave combine: waves 0&2 share m-rows 0..63 (different wn), 1&3 share 64..127.
  float* red = (float*)sA;                       // 512B scratch (K-loop done with sA)
  if (wave >= 2 && colq == 0) {                  // wn=64 waves publish
#pragma unroll
    for (int mt = 0; mt < 2; mt++)
#pragma unroll
      for (int q = 0; q < 4; q++) {
        float4 v;
        v.x = sval[mt][q * 4 + 0]; v.y = sval[mt][q * 4 + 1];
        v.z = sval[mt][q * 4 + 2]; v.w = sval[mt][q * 4 + 3];
        *(float4*)(red + wm + mt * 32 + q * 8 + 4 * hi) = v;   // rows q*8+4hi+{0..3}
      }
  }
  __syncthreads();
  if (wave < 2 && colq == 0) {                   // wn=0 waves combine + store
    float* pbase = part + (((size_t)nblk * ROLES + r) << 12) + m0;  // part[nblk][r][m]
#pragma unroll
    for (int mt = 0; mt < 2; mt++)
#pragma unroll
      for (int q = 0; q < 4; q++) {
        const int row = wm + mt * 32 + q * 8 + 4 * hi;
        const float4 rv = *(const float4*)(red + row);
        float4 v;
        v.x = sval[mt][q * 4 + 0] + rv.x;
        v.y = sval[mt][q * 4 + 1] + rv.y;
        v.z = sval[mt][q * 4 + 2] + rv.z;
        v.w = sval[mt][q * 4 + 3] + rv.w;
        *(float4*)(pbase + row) = v;
      }
  }
}

// ---- reduce: out[m,r] = sum_nb part[nb][r][m] + bias2[r] ------------------
__global__ __launch_bounds__(256) void reduce_k(const float* __restrict__ part,
                                                const float* __restrict__ b2,
                                                float* __restrict__ out) {
  const int idx = blockIdx.x * 256 + threadIdx.x;   // 262144 = NTOK*ROLES
  const int m = idx >> 6, r = idx & (ROLES - 1);
  float v = b2[r];
#pragma unroll
  for (int nb = 0; nb < 4; nb++)
    v += part[(((size_t)nb * ROLES + r) << 12) + m];
  out[idx] = v;                                   // out[m*64+r] == out[idx]
}

// ---- correctness fallback if workspace is too small (slow, pure fp32) -----
__global__ __launch_bounds__(256) void fallback_k(
    const float* __restrict__ pred, const float* __restrict__ args,
    const float* __restrict__ U, const float* __restrict__ b1,
    const float* __restrict__ b2, float* __restrict__ out) {
  const int idx = blockIdx.x * 256 + threadIdx.x;   // 262144
  const int r = idx >> 12;                          // block-uniform role
  const int n = idx & (NTOK - 1);
  const float* arow = args + (size_t)n * HID;
  const float* prow = pred + (size_t)n * HID;
  float acc = 0.f;
  for (int h = 0; h < HID; h++) {
    const float* urow = U + ((size_t)h * ROLES + r) * HID;
    float s = 0.f;
    for (int k = 0; k < HID; k++) s = fmaf(urow[k], arow[k], s);
    acc = fmaf(prow[h], s, acc);
  }
  float sb = 0.f;
  const float* brow = b1 + (size_t)r * HID;
  for (int k = 0; k < HID; k++) sb = fmaf(brow[k], arow[k], sb);
  out[(size_t)n * ROLES + r] = acc + sb + b2[r];
}

extern "C" void kernel_launch(void* const* d_in, const int* in_sizes, int n_in,
                              void* d_out, int out_size, void* d_ws, size_t ws_size,
                              hipStream_t stream) {
  const float* pred = (const float*)d_in[0];
  const float* args = (const float*)d_in[1];
  const float* U    = (const float*)d_in[2];
  const float* b1   = (const float*)d_in[3];
  const float* b2   = (const float*)d_in[4];
  float* out = (float*)d_out;

  const size_t PRED_ELEMS = (size_t)NTOK * HID;         // 2,097,152
  const size_t U_ELEMS    = (size_t)HID * ROLES * HID;  // 16,777,216
  const size_t PART_ELEMS = (size_t)4 * ROLES * NTOK;   // 1,048,576 f32 (4 MiB)
  const size_t WS_NEEDED  = (PRED_ELEMS + U_ELEMS) * sizeof(_Float16)
                          + PART_ELEMS * sizeof(float); // ~40 MiB

  if (ws_size < WS_NEEDED) {
    hipLaunchKernelGGL(fallback_k, dim3((NTOK * ROLES) / 256), dim3(256), 0, stream,
                       pred, args, U, b1, b2, out);
    return;
  }

  _Float16* predf = (_Float16*)d_ws;
  _Float16* utf   = predf + PRED_ELEMS;
  float*    partb = (float*)(utf + U_ELEMS);

  hipLaunchKernelGGL(prep_fused, dim3(4096), dim3(256), 0, stream,
                     pred, predf, U, utf);
  hipLaunchKernelGGL(bilinear_mfma, dim3(HID / BN, NTOK / BM, ROLES), dim3(256), 0, stream,
                     predf, utf, args, b1, partb);
  hipLaunchKernelGGL(reduce_k, dim3((NTOK * ROLES) / 256), dim3(256), 0, stream,
                     partb, b2, out);
}

// Round 8
// 297.872 us; speedup vs baseline: 1.0648x; 1.0648x over previous
//
#include <hip/hip_runtime.h>
#include <stdint.h>

// BilinearScorer: out[n,r] = sum_{h,k} pred[n,h] U[h,r,k] args[n,k] + bias1[r,:].args[n,:] + bias2[r]
// n=4096, h=k=512, R=64.  137.4 GFLOP fp32-equivalent.
// R13 = revert R12 shape (32x32 reader had 4-way conflicts on EVERY read: 2^24
// conflict-cycles/dispatch, main 175->215us) + BK 64->32 DOUBLE-BUFFER, 1 barrier/step.
// Mechanism (T3 minimum-2-phase): old schedule drained vmcnt right after issuing
// stages (full L2 latency exposed at every barrier). New: STAGE(next buf) -> compute
// (cur buf) -> barrier; loads have the whole MFMA phase (~300cy > ~200cy L2 hit) in
// flight. Same LDS total (32KB), same occupancy, same MFMA/ds_read counts.
// Swizzle for 64B rows: slot = quad ^ ((col>>1)&3); all 8 lanes of a read phase hit
// distinct 4-word bank groups (enumerated). Staging pre-applies the inverse on the
// global source (rule #21: both sides, same involution).
// R10 lesson: no per-block device-scope fences. R5: (256,3) unified reg cap.

#define HID   512
#define ROLES 64
#define NTOK  4096
#define BM    128
#define BN    128
#define BK    32

typedef __attribute__((ext_vector_type(8))) _Float16 f16x8;  // MFMA A/B operand: 4 VGPRs
typedef __attribute__((ext_vector_type(4))) _Float16 f16x4;
typedef __attribute__((ext_vector_type(4))) float    f32x4;

__device__ __forceinline__ void async16(const void* g, void* l) {
  // global -> LDS direct copy, 16B/lane. LDS dest is wave-uniform base + lane*16;
  // per-lane SOURCE address is free (implements the store-side swizzle).
  __builtin_amdgcn_global_load_lds(
      (const __attribute__((address_space(1))) uint32_t*)g,
      (__attribute__((address_space(3))) uint32_t*)l, 16, 0, 0);
}

// ---- fused prep: blocks [0,2048) transpose U; [2048,4096) convert pred ----
__global__ __launch_bounds__(256) void prep_fused(
    const float* __restrict__ pred_in, _Float16* __restrict__ predf,
    const float* __restrict__ U, _Float16* __restrict__ ut) {
  __shared__ float tile[128][65];                // pad 65: col-reads 4-way max
  const int bx = blockIdx.x;
  const int t  = threadIdx.x;

  if (bx >= 2048) {                              // ---- cvt_pred path ----
    const int idx = (bx - 2048) * 256 + t;       // 2048 blocks x 256 x float4
    const float4 v = ((const float4*)pred_in)[idx];
    f16x4 o;
    o[0] = (_Float16)v.x; o[1] = (_Float16)v.y;
    o[2] = (_Float16)v.z; o[3] = (_Float16)v.w;
    ((f16x4*)predf)[idx] = o;
    return;
  }

  // ---- cvt_u path: grid-flattened (kb 8, hb 4, r 64) ----
  const int kb = bx & 7, hb = (bx >> 3) & 3, r = bx >> 5;
  const int h0 = hb * 128, k0 = kb * 64;
  const int rr = t >> 4, c4 = (t & 15) * 4;
#pragma unroll
  for (int pass = 0; pass < 8; pass++) {
    const int row = pass * 16 + rr;
    const float4 v = *(const float4*)(U + ((size_t)(h0 + row) * ROLES + r) * HID + k0 + c4);
    tile[row][c4 + 0] = v.x; tile[row][c4 + 1] = v.y;
    tile[row][c4 + 2] = v.z; tile[row][c4 + 3] = v.w;
  }
  __syncthreads();
  const int kr = t >> 4, hc = (t & 15) * 8;
#pragma unroll
  for (int pass = 0; pass < 4; pass++) {
    const int k = pass * 16 + kr;
    alignas(16) _Float16 hbuf[8];
#pragma unroll
    for (int j = 0; j < 8; j++) hbuf[j] = (_Float16)tile[hc + j][k];
    *(uint4*)(ut + ((size_t)r * HID + k0 + k) * HID + h0 + hc) = *(const uint4*)hbuf;
  }
}

// ---- main fused GEMM: BK=32, double-buffered, one barrier per K-step ------
__global__ __launch_bounds__(256, 3) void bilinear_mfma(
    const _Float16* __restrict__ predf, const _Float16* __restrict__ utf,
    const float* __restrict__ args, const float* __restrict__ bias1,
    float* __restrict__ part) {
  __shared__ _Float16 sA[2][BM * BK];            // 2 x 8 KB
  __shared__ _Float16 sB[2][BN * BK];            // 2 x 8 KB

  const int nblk = blockIdx.x, mblk = blockIdx.y, r = blockIdx.z;
  const int m0 = mblk * BM, n0 = nblk * BN;
  const int tid  = threadIdx.x;
  const int wave = tid >> 6, lane = tid & 63;
  const int col  = lane & 15, quad = lane >> 4;
  const int wm = (wave & 1) * 64, wn = (wave >> 1) * 64;

  // staging: tile = 128 rows x 32 f16 (64B/row) = 4 chunks/row. Per call, 256
  // lanes cover 64 rows x 4 slots; 2 calls per operand per step. LDS slot s of
  // row i holds global chunk s ^ ((i>>1)&3)  (involution).
  const int i4 = tid >> 2;                       // row 0..63 within call (+64/call)
  const int s4 = tid & 3;                        // LDS slot
  const int gch = s4 ^ ((i4 >> 1) & 3);          // global chunk for this slot
  const size_t offA = (size_t)(m0 + i4) * HID + gch * 8;
  const size_t offB = ((size_t)r * HID + n0 + i4) * HID + gch * 8;
  const int ldsOff = tid * 8;                    // f16; = wave-base + lane*16B

  // reader: frag row = base + col (base ≡ 0 mod 16) -> (row>>1)&3 = (col>>1)&3.
  // chunk needed = quad; swizzled slot = quad ^ ((col>>1)&3).
  // Bank check (8-lane phases): even rows half0 + 4 distinct slots, odd rows
  // half1 + 4 distinct slots -> all 32 banks exactly once. Conflict-free.
  const int slot8 = (quad ^ ((col >> 1) & 3)) * 8;
  int rowA[4], rowB[4];
#pragma unroll
  for (int mt = 0; mt < 4; mt++) rowA[mt] = (wm + mt * 16 + col) * BK + slot8;
#pragma unroll
  for (int nt = 0; nt < 4; nt++) rowB[nt] = (wn + nt * 16 + col) * BK + slot8;

  f32x4 acc[4][4];
#pragma unroll
  for (int a = 0; a < 4; a++)
#pragma unroll
    for (int b = 0; b < 4; b++) acc[a][b] = (f32x4){0.f, 0.f, 0.f, 0.f};

  const _Float16* curA = sA[0]; _Float16* nxtA = sA[1];
  const _Float16* curB = sB[0]; _Float16* nxtB = sB[1];

  // prologue: stage tile 0 into buf0
  async16(predf + offA,                  (void*)(sA[0] + ldsOff));
  async16(predf + offA + (size_t)64 * HID, (void*)(sA[0] + 2048 + ldsOff));
  async16(utf   + offB,                  (void*)(sB[0] + ldsOff));
  async16(utf   + offB + (size_t)64 * HID, (void*)(sB[0] + 2048 + ldsOff));
  __syncthreads();                               // drains vmcnt: buf0 ready

  for (int t = 0; t < 15; t++) {
    const int k1 = (t + 1) * BK;
    // issue next-tile stages FIRST (they fly during the MFMA phase)
    async16(predf + offA + k1,                    (void*)(nxtA + ldsOff));
    async16(predf + offA + (size_t)64 * HID + k1, (void*)(nxtA + 2048 + ldsOff));
    async16(utf   + offB + k1,                    (void*)(nxtB + ldsOff));
    async16(utf   + offB + (size_t)64 * HID + k1, (void*)(nxtB + 2048 + ldsOff));

    // compute current tile: 8 ds_read_b128 + 16 MFMA (full K=32 per mfma)
    {
      f16x8 a[4], b[4];
#pragma unroll
      for (int mt = 0; mt < 4; mt++) a[mt] = *(const f16x8*)(curA + rowA[mt]);
#pragma unroll
      for (int nt = 0; nt < 4; nt++) b[nt] = *(const f16x8*)(curB + rowB[nt]);
#pragma unroll
      for (int mt = 0; mt < 4; mt++)
#pragma unroll
        for (int nt = 0; nt < 4; nt++)
          acc[mt][nt] = __builtin_amdgcn_mfma_f32_16x16x32_f16(a[mt], b[nt], acc[mt][nt], 0, 0, 0);
    }
    __syncthreads();                             // reads done + next stage landed
    const _Float16* tA = curA; curA = nxtA; nxtA = (_Float16*)tA;
    const _Float16* tB = curB; curB = nxtB; nxtB = (_Float16*)tB;
  }
  {                                              // final tile (no prefetch)
    f16x8 a[4], b[4];
#pragma unroll
    for (int mt = 0; mt < 4; mt++) a[mt] = *(const f16x8*)(curA + rowA[mt]);
#pragma unroll
    for (int nt = 0; nt < 4; nt++) b[nt] = *(const f16x8*)(curB + rowB[nt]);
#pragma unroll
    for (int mt = 0; mt < 4; mt++)
#pragma unroll
      for (int nt = 0; nt < 4; nt++)
        acc[mt][nt] = __builtin_amdgcn_mfma_f32_16x16x32_f16(a[mt], b[nt], acc[mt][nt], 0, 0, 0);
  }

  // epilogue (R11-verified): sval = sum over wave's n-cols of (T+bias1)*args,
  // 16-lane shfl reduce; cross-wave combine via LDS; one float4 store per mt.
  // Final compute read sA[1]/sB[1] (15 swaps) -> red scratch in sA[0] is disjoint.
  float b1v[4];
#pragma unroll
  for (int nt = 0; nt < 4; nt++)
    b1v[nt] = bias1[r * HID + n0 + wn + nt * 16 + col];

  float sval[4][4];
#pragma unroll
  for (int mt = 0; mt < 4; mt++) {
#pragma unroll
    for (int reg = 0; reg < 4; reg++) {
      const int m = m0 + wm + mt * 16 + quad * 4 + reg;   // C/D row = quad*4+reg (m89)
      const float* arow = args + (size_t)m * HID + n0 + wn + col;
      float s = 0.f;
#pragma unroll
      for (int nt = 0; nt < 4; nt++)
        s += (acc[mt][nt][reg] + b1v[nt]) * arow[nt * 16];
      s += __shfl_xor(s, 1);
      s += __shfl_xor(s, 2);
      s += __shfl_xor(s, 4);
      s += __shfl_xor(s, 8);                     // reduce 16-lane col group
      sval[mt][reg] = s;
    }
  }

  float* red = (float*)sA[0];                    // 512B scratch, disjoint from buf1
  if (wave >= 2 && col == 0) {                   // wn=64 waves publish
#pragma unroll
    for (int mt = 0; mt < 4; mt++)
#pragma unroll
      for (int reg = 0; reg < 4; reg++)
        red[wm + mt * 16 + quad * 4 + reg] = sval[mt][reg];
  }
  __syncthreads();
  if (wave < 2 && col == 0) {                    // wn=0 waves combine + store
    float* pbase = part + (((size_t)nblk * ROLES + r) << 12) + m0;  // part[nblk][r][m]
#pragma unroll
    for (int mt = 0; mt < 4; mt++) {
      const int row = wm + mt * 16 + quad * 4;
      float4 v;
      v.x = sval[mt][0] + red[row + 0];
      v.y = sval[mt][1] + red[row + 1];
      v.z = sval[mt][2] + red[row + 2];
      v.w = sval[mt][3] + red[row + 3];
      *(float4*)(pbase + row) = v;
    }
  }
}

// ---- reduce: out[m,r] = sum_nb part[nb][r][m] + bias2[r] ------------------
__global__ __launch_bounds__(256) void reduce_k(const float* __restrict__ part,
                                                const float* __restrict__ b2,
                                                float* __restrict__ out) {
  const int idx = blockIdx.x * 256 + threadIdx.x;   // 262144 = NTOK*ROLES
  const int m = idx >> 6, r = idx & (ROLES - 1);
  float v = b2[r];
#pragma unroll
  for (int nb = 0; nb < 4; nb++)
    v += part[(((size_t)nb * ROLES + r) << 12) + m];
  out[idx] = v;                                   // out[m*64+r] == out[idx]
}

// ---- correctness fallback if workspace is too small (slow, pure fp32) -----
__global__ __launch_bounds__(256) void fallback_k(
    const float* __restrict__ pred, const float* __restrict__ args,
    const float* __restrict__ U, const float* __restrict__ b1,
    const float* __restrict__ b2, float* __restrict__ out) {
  const int idx = blockIdx.x * 256 + threadIdx.x;   // 262144
  const int r = idx >> 12;                          // block-uniform role
  const int n = idx & (NTOK - 1);
  const float* arow = args + (size_t)n * HID;
  const float* prow = pred + (size_t)n * HID;
  float acc = 0.f;
  for (int h = 0; h < HID; h++) {
    const float* urow = U + ((size_t)h * ROLES + r) * HID;
    float s = 0.f;
    for (int k = 0; k < HID; k++) s = fmaf(urow[k], arow[k], s);
    acc = fmaf(prow[h], s, acc);
  }
  float sb = 0.f;
  const float* brow = b1 + (size_t)r * HID;
  for (int k = 0; k < HID; k++) sb = fmaf(brow[k], arow[k], sb);
  out[(size_t)n * ROLES + r] = acc + sb + b2[r];
}

extern "C" void kernel_launch(void* const* d_in, const int* in_sizes, int n_in,
                              void* d_out, int out_size, void* d_ws, size_t ws_size,
                              hipStream_t stream) {
  const float* pred = (const float*)d_in[0];
  const float* args = (const float*)d_in[1];
  const float* U    = (const float*)d_in[2];
  const float* b1   = (const float*)d_in[3];
  const float* b2   = (const float*)d_in[4];
  float* out = (float*)d_out;

  const size_t PRED_ELEMS = (size_t)NTOK * HID;         // 2,097,152
  const size_t U_ELEMS    = (size_t)HID * ROLES * HID;  // 16,777,216
  const size_t PART_ELEMS = (size_t)4 * ROLES * NTOK;   // 1,048,576 f32 (4 MiB)
  const size_t WS_NEEDED  = (PRED_ELEMS + U_ELEMS) * sizeof(_Float16)
                          + PART_ELEMS * sizeof(float); // ~40 MiB

  if (ws_size < WS_NEEDED) {
    hipLaunchKernelGGL(fallback_k, dim3((NTOK * ROLES) / 256), dim3(256), 0, stream,
                       pred, args, U, b1, b2, out);
    return;
  }

  _Float16* predf = (_Float16*)d_ws;
  _Float16* utf   = predf + PRED_ELEMS;
  float*    partb = (float*)(utf + U_ELEMS);

  hipLaunchKernelGGL(prep_fused, dim3(4096), dim3(256), 0, stream,
                     pred, predf, U, utf);
  hipLaunchKernelGGL(bilinear_mfma, dim3(HID / BN, NTOK / BM, ROLES), dim3(256), 0, stream,
                     predf, utf, args, b1, partb);
  hipLaunchKernelGGL(reduce_k, dim3((NTOK * ROLES) / 256), dim3(256), 0, stream,
                     partb, b2, out);
}

// Round 9
// 267.060 us; speedup vs baseline: 1.1877x; 1.1154x over previous
//
#include <hip/hip_runtime.h>
#include <stdint.h>

// BilinearScorer: out[n,r] = sum_{h,k} pred[n,h] U[h,r,k] args[n,k] + bias1[r,:].args[n,:] + bias2[r]
// n=4096, h=k=512, R=64.  137.4 GFLOP fp32-equivalent.
// R14 = 256^2 8-wave deep-pipeline port (T3+T4+T5 on top of verified T2 swizzle).
// R13 post-mortem: BK=32 dbuf halved MFMA/barrier and doubled barriers -> 194us
// (corpus m139/m131: 128^2 2-barrier family is ceiling-locked; escape = 256^2 schedule).
// Design: BM=BN=256 BK=64, 512thr/8 waves (2Mx4N), acc[8][4] f32x4, LDS 2x64KB dbuf,
// 1 block/CU. Per K-tile: 4 quadrant phases {ds_read subtile; setprio(1); 16 MFMA;
// setprio(0); s_barrier}, then STAGE(t+2 -> freed buf; 8 gload_lds) + s_waitcnt
// vmcnt(8) (tile t+1 landed, t+2 in flight - NEVER drain to 0 mid-loop) + s_barrier.
// vmcnt ledger (8 vm-ops/tile/wave, in-order retirement): prologue STAGE(0)+STAGE(1),
// vmcnt(8)=tile0 ready; iter t<6: +8 ops, vmcnt(8)=tile t+1 ready; t=6: vmcnt(0)
// drains tile 7; t=7: nothing outstanding. Staging/reader swizzle = R11's proven
// 0-conflict formulas (row==col mod 8 invariants hold at wm in {0,128}).
// No fences/atomics (R10 lesson). All waits are asm volatile w/ "memory" clobber.

#define HID   512
#define ROLES 64
#define NTOK  4096
#define BM    256
#define BN    256
#define BK    64

typedef __attribute__((ext_vector_type(8))) _Float16 f16x8;  // MFMA A/B operand: 4 VGPRs
typedef __attribute__((ext_vector_type(4))) _Float16 f16x4;
typedef __attribute__((ext_vector_type(4))) float    f32x4;

__device__ __forceinline__ void async16(const void* g, void* l) {
  // global -> LDS direct copy, 16B/lane. LDS dest is wave-uniform base + lane*16;
  // per-lane SOURCE address is free (implements the store-side swizzle).
  __builtin_amdgcn_global_load_lds(
      (const __attribute__((address_space(1))) uint32_t*)g,
      (__attribute__((address_space(3))) uint32_t*)l, 16, 0, 0);
}

// ---- fused prep: blocks [0,2048) transpose U; [2048,4096) convert pred ----
__global__ __launch_bounds__(256) void prep_fused(
    const float* __restrict__ pred_in, _Float16* __restrict__ predf,
    const float* __restrict__ U, _Float16* __restrict__ ut) {
  __shared__ float tile[128][65];                // pad 65: col-reads 4-way max
  const int bx = blockIdx.x;
  const int t  = threadIdx.x;

  if (bx >= 2048) {                              // ---- cvt_pred path ----
    const int idx = (bx - 2048) * 256 + t;       // 2048 blocks x 256 x float4
    const float4 v = ((const float4*)pred_in)[idx];
    f16x4 o;
    o[0] = (_Float16)v.x; o[1] = (_Float16)v.y;
    o[2] = (_Float16)v.z; o[3] = (_Float16)v.w;
    ((f16x4*)predf)[idx] = o;
    return;
  }

  // ---- cvt_u path: grid-flattened (kb 8, hb 4, r 64) ----
  const int kb = bx & 7, hb = (bx >> 3) & 3, r = bx >> 5;
  const int h0 = hb * 128, k0 = kb * 64;
  const int rr = t >> 4, c4 = (t & 15) * 4;
#pragma unroll
  for (int pass = 0; pass < 8; pass++) {
    const int row = pass * 16 + rr;
    const float4 v = *(const float4*)(U + ((size_t)(h0 + row) * ROLES + r) * HID + k0 + c4);
    tile[row][c4 + 0] = v.x; tile[row][c4 + 1] = v.y;
    tile[row][c4 + 2] = v.z; tile[row][c4 + 3] = v.w;
  }
  __syncthreads();
  const int kr = t >> 4, hc = (t & 15) * 8;
#pragma unroll
  for (int pass = 0; pass < 4; pass++) {
    const int k = pass * 16 + kr;
    alignas(16) _Float16 hbuf[8];
#pragma unroll
    for (int j = 0; j < 8; j++) hbuf[j] = (_Float16)tile[hc + j][k];
    *(uint4*)(ut + ((size_t)r * HID + k0 + k) * HID + h0 + hc) = *(const uint4*)hbuf;
  }
}

// ---- main fused GEMM: 256^2 tile, 8 waves, 4-phase/K-tile, counted vmcnt ---
__global__ __launch_bounds__(512, 2) void bilinear_mfma(
    const _Float16* __restrict__ predf, const _Float16* __restrict__ utf,
    const float* __restrict__ args, const float* __restrict__ bias1,
    float* __restrict__ part) {
  // [buf][ A: 0..16383 | B: 16384..32767 ] f16 ; 2 x 64KB = 128KB
  __shared__ _Float16 lds[2][32768];

  const int nblk = blockIdx.x, mblk = blockIdx.y, r = blockIdx.z;
  const int m0 = mblk * BM, n0 = nblk * BN;
  const int tid  = threadIdx.x;
  const int lane = tid & 63, wid = tid >> 6;
  const int col  = lane & 15, quad = lane >> 4;
  const int wr = wid >> 2, wc = wid & 3;         // 2 M-bands x 4 N-bands
  const int wm = wr * 128, wn = wc * 64;

  // staging: per call 512 lanes cover 64 rows x 8 chunk-slots; 4 calls (c) per
  // operand per K-tile (rows += 64). LDS slot s of row i holds chunk s ^ (i&7).
  const int i_loc = tid >> 3;                    // 0..63
  const int ko    = ((tid & 7) ^ (i_loc & 7)) * 8;
  const size_t offA = (size_t)(m0 + i_loc) * HID + ko;
  const size_t offB = ((size_t)r * HID + n0 + i_loc) * HID + ko;
  const int ldsOff = tid * 8;                    // f16: wave-uniform + lane*16B

  // reader (R11-verified): chunk q at slot q ^ (row&7); row&7 == col&7.
  const int slotL8 = (quad ^ (col & 7)) * 8;     // k in [0,32)
  const int slotH8 = slotL8 ^ 32;                // k in [32,64)
  int rowA[8], rowB[4];
#pragma unroll
  for (int mt = 0; mt < 8; mt++) rowA[mt] = (wm + mt * 16 + col) * BK;
#pragma unroll
  for (int nt = 0; nt < 4; nt++) rowB[nt] = (wn + nt * 16 + col) * BK;

  f32x4 acc[8][4];
#pragma unroll
  for (int a = 0; a < 8; a++)
#pragma unroll
    for (int b = 0; b < 4; b++) acc[a][b] = (f32x4){0.f, 0.f, 0.f, 0.f};

  auto STAGE = [&](int t, int buf) {             // 8 gload_lds per thread
    _Float16* bA = &lds[buf][0];
    _Float16* bB = &lds[buf][16384];
    const size_t kof = (size_t)t * BK;
#pragma unroll
    for (int c = 0; c < 4; c++) {
      async16(predf + offA + (size_t)(c * 64) * HID + kof, bA + c * 4096 + ldsOff);
      async16(utf   + offB + (size_t)(c * 64) * HID + kof, bB + c * 4096 + ldsOff);
    }
  };

  // prologue: tiles 0,1 staged; wait tile0 only (tile1 stays in flight)
  STAGE(0, 0);
  STAGE(1, 1);
  asm volatile("s_waitcnt vmcnt(8)" ::: "memory");
  __builtin_amdgcn_s_barrier();
  __builtin_amdgcn_sched_barrier(0);

  for (int t = 0; t < 8; ++t) {
    const _Float16* bA = &lds[t & 1][0];
    const _Float16* bB = &lds[t & 1][16384];

    f16x8 aL[4], aH[4], bL[2], bH[2], cL[2], cH[2];

    // phase 1: mt 0-3 x nt 0-1 (12 ds_read_b128, 16 MFMA)
#pragma unroll
    for (int mt = 0; mt < 4; mt++) {
      aL[mt] = *(const f16x8*)(bA + rowA[mt] + slotL8);
      aH[mt] = *(const f16x8*)(bA + rowA[mt] + slotH8);
    }
#pragma unroll
    for (int nt = 0; nt < 2; nt++) {
      bL[nt] = *(const f16x8*)(bB + rowB[nt] + slotL8);
      bH[nt] = *(const f16x8*)(bB + rowB[nt] + slotH8);
    }
    __builtin_amdgcn_s_setprio(1);
#pragma unroll
    for (int mt = 0; mt < 4; mt++)
#pragma unroll
      for (int nt = 0; nt < 2; nt++) {
        acc[mt][nt] = __builtin_amdgcn_mfma_f32_16x16x32_f16(aL[mt], bL[nt], acc[mt][nt], 0, 0, 0);
        acc[mt][nt] = __builtin_amdgcn_mfma_f32_16x16x32_f16(aH[mt], bH[nt], acc[mt][nt], 0, 0, 0);
      }
    __builtin_amdgcn_s_setprio(0);
    __builtin_amdgcn_s_barrier();
    __builtin_amdgcn_sched_barrier(0);

    // phase 2: mt 0-3 x nt 2-3 (4 reads, 16 MFMA)
#pragma unroll
    for (int nt = 0; nt < 2; nt++) {
      cL[nt] = *(const f16x8*)(bB + rowB[nt + 2] + slotL8);
      cH[nt] = *(const f16x8*)(bB + rowB[nt + 2] + slotH8);
    }
    __builtin_amdgcn_s_setprio(1);
#pragma unroll
    for (int mt = 0; mt < 4; mt++)
#pragma unroll
      for (int nt = 0; nt < 2; nt++) {
        acc[mt][nt + 2] = __builtin_amdgcn_mfma_f32_16x16x32_f16(aL[mt], cL[nt], acc[mt][nt + 2], 0, 0, 0);
        acc[mt][nt + 2] = __builtin_amdgcn_mfma_f32_16x16x32_f16(aH[mt], cH[nt], acc[mt][nt + 2], 0, 0, 0);
      }
    __builtin_amdgcn_s_setprio(0);
    __builtin_amdgcn_s_barrier();
    __builtin_amdgcn_sched_barrier(0);

    // phase 3: mt 4-7 x nt 2-3 (8 reads, 16 MFMA)
#pragma unroll
    for (int mt = 0; mt < 4; mt++) {
      aL[mt] = *(const f16x8*)(bA + rowA[mt + 4] + slotL8);
      aH[mt] = *(const f16x8*)(bA + rowA[mt + 4] + slotH8);
    }
    __builtin_amdgcn_s_setprio(1);
#pragma unroll
    for (int mt = 0; mt < 4; mt++)
#pragma unroll
      for (int nt = 0; nt < 2; nt++) {
        acc[mt + 4][nt + 2] = __builtin_amdgcn_mfma_f32_16x16x32_f16(aL[mt], cL[nt], acc[mt + 4][nt + 2], 0, 0, 0);
        acc[mt + 4][nt + 2] = __builtin_amdgcn_mfma_f32_16x16x32_f16(aH[mt], cH[nt], acc[mt + 4][nt + 2], 0, 0, 0);
      }
    __builtin_amdgcn_s_setprio(0);
    __builtin_amdgcn_s_barrier();
    __builtin_amdgcn_sched_barrier(0);

    // phase 4: mt 4-7 x nt 0-1 (4 reads, 16 MFMA)
#pragma unroll
    for (int nt = 0; nt < 2; nt++) {
      bL[nt] = *(const f16x8*)(bB + rowB[nt] + slotL8);
      bH[nt] = *(const f16x8*)(bB + rowB[nt] + slotH8);
    }
    __builtin_amdgcn_s_setprio(1);
#pragma unroll
    for (int mt = 0; mt < 4; mt++)
#pragma unroll
      for (int nt = 0; nt < 2; nt++) {
        acc[mt + 4][nt] = __builtin_amdgcn_mfma_f32_16x16x32_f16(aL[mt], bL[nt], acc[mt + 4][nt], 0, 0, 0);
        acc[mt + 4][nt] = __builtin_amdgcn_mfma_f32_16x16x32_f16(aH[mt], bH[nt], acc[mt + 4][nt], 0, 0, 0);
      }
    __builtin_amdgcn_s_setprio(0);
    __builtin_amdgcn_s_barrier();                // all waves done reading buf[t&1]
    __builtin_amdgcn_sched_barrier(0);

    if (t < 6) {
      STAGE(t + 2, t & 1);                       // overwrite just-freed buffer
      asm volatile("s_waitcnt vmcnt(8)" ::: "memory");   // tile t+1 landed
    } else if (t == 6) {
      asm volatile("s_waitcnt vmcnt(0)" ::: "memory");   // drain tile 7 (tail)
    }
    __builtin_amdgcn_s_barrier();                // consensus: next buf ready
    __builtin_amdgcn_sched_barrier(0);
  }

  // epilogue: s = sum over wave's 64 n-cols of (T + bias1)*args, 16-lane shfl
  // reduce; 4 waves share each 128-row band -> 3 publish via LDS, wc==0 combines.
  float b1v[4];
#pragma unroll
  for (int nt = 0; nt < 4; nt++)
    b1v[nt] = bias1[r * HID + n0 + wn + nt * 16 + col];

  float sval[8][4];
#pragma unroll
  for (int mt = 0; mt < 8; mt++) {
#pragma unroll
    for (int reg = 0; reg < 4; reg++) {
      const int m = m0 + wm + mt * 16 + quad * 4 + reg;   // C/D row = quad*4+reg (m89)
      const float* arow = args + (size_t)m * HID + n0 + wn + col;
      float s = 0.f;
#pragma unroll
      for (int nt = 0; nt < 4; nt++)
        s += (acc[mt][nt][reg] + b1v[nt]) * arow[nt * 16];
      s += __shfl_xor(s, 1);
      s += __shfl_xor(s, 2);
      s += __shfl_xor(s, 4);
      s += __shfl_xor(s, 8);                     // reduce 16-lane col group
      sval[mt][reg] = s;
    }
  }

  float* red = (float*)&lds[0][0];               // 3 x 256 f32 = 3KB scratch
  if (wc != 0 && col == 0) {                     // 3 publisher waves per band
#pragma unroll
    for (int mt = 0; mt < 8; mt++)
#pragma unroll
      for (int reg = 0; reg < 4; reg++)
        red[(wc - 1) * 256 + wm + mt * 16 + quad * 4 + reg] = sval[mt][reg];
  }
  __syncthreads();
  if (wc == 0 && col == 0) {                     // combiner waves (wid 0, 4)
    float* pbase = part + (((size_t)nblk * ROLES + r) << 12) + m0;  // part[nblk][r][m]
#pragma unroll
    for (int mt = 0; mt < 8; mt++) {
      const int row = wm + mt * 16 + quad * 4;
      float4 v;
      v.x = sval[mt][0] + red[row + 0] + red[256 + row + 0] + red[512 + row + 0];
      v.y = sval[mt][1] + red[row + 1] + red[256 + row + 1] + red[512 + row + 1];
      v.z = sval[mt][2] + red[row + 2] + red[256 + row + 2] + red[512 + row + 2];
      v.w = sval[mt][3] + red[row + 3] + red[256 + row + 3] + red[512 + row + 3];
      *(float4*)(pbase + row) = v;
    }
  }
}

// ---- reduce: out[m,r] = sum_nb part[nb][r][m] + bias2[r] ------------------
__global__ __launch_bounds__(256) void reduce_k(const float* __restrict__ part,
                                                const float* __restrict__ b2,
                                                float* __restrict__ out) {
  const int idx = blockIdx.x * 256 + threadIdx.x;   // 262144 = NTOK*ROLES
  const int m = idx >> 6, r = idx & (ROLES - 1);
  float v = b2[r];
#pragma unroll
  for (int nb = 0; nb < 2; nb++)
    v += part[(((size_t)nb * ROLES + r) << 12) + m];
  out[idx] = v;                                   // out[m*64+r] == out[idx]
}

// ---- correctness fallback if workspace is too small (slow, pure fp32) -----
__global__ __launch_bounds__(256) void fallback_k(
    const float* __restrict__ pred, const float* __restrict__ args,
    const float* __restrict__ U, const float* __restrict__ b1,
    const float* __restrict__ b2, float* __restrict__ out) {
  const int idx = blockIdx.x * 256 + threadIdx.x;   // 262144
  const int r = idx >> 12;                          // block-uniform role
  const int n = idx & (NTOK - 1);
  const float* arow = args + (size_t)n * HID;
  const float* prow = pred + (size_t)n * HID;
  float acc = 0.f;
  for (int h = 0; h < HID; h++) {
    const float* urow = U + ((size_t)h * ROLES + r) * HID;
    float s = 0.f;
    for (int k = 0; k < HID; k++) s = fmaf(urow[k], arow[k], s);
    acc = fmaf(prow[h], s, acc);
  }
  float sb = 0.f;
  const float* brow = b1 + (size_t)r * HID;
  for (int k = 0; k < HID; k++) sb = fmaf(brow[k], arow[k], sb);
  out[(size_t)n * ROLES + r] = acc + sb + b2[r];
}

extern "C" void kernel_launch(void* const* d_in, const int* in_sizes, int n_in,
                              void* d_out, int out_size, void* d_ws, size_t ws_size,
                              hipStream_t stream) {
  const float* pred = (const float*)d_in[0];
  const float* args = (const float*)d_in[1];
  const float* U    = (const float*)d_in[2];
  const float* b1   = (const float*)d_in[3];
  const float* b2   = (const float*)d_in[4];
  float* out = (float*)d_out;

  const size_t PRED_ELEMS = (size_t)NTOK * HID;         // 2,097,152
  const size_t U_ELEMS    = (size_t)HID * ROLES * HID;  // 16,777,216
  const size_t PART_ELEMS = (size_t)2 * ROLES * NTOK;   // 524,288 f32 (2 MiB)
  const size_t WS_NEEDED  = (PRED_ELEMS + U_ELEMS) * sizeof(_Float16)
                          + PART_ELEMS * sizeof(float); // ~38 MiB

  if (ws_size < WS_NEEDED) {
    hipLaunchKernelGGL(fallback_k, dim3((NTOK * ROLES) / 256), dim3(256), 0, stream,
                       pred, args, U, b1, b2, out);
    return;
  }

  _Float16* predf = (_Float16*)d_ws;
  _Float16* utf   = predf + PRED_ELEMS;
  float*    partb = (float*)(utf + U_ELEMS);

  hipLaunchKernelGGL(prep_fused, dim3(4096), dim3(256), 0, stream,
                     pred, predf, U, utf);
  hipLaunchKernelGGL(bilinear_mfma, dim3(HID / BN, NTOK / BM, ROLES), dim3(512), 0, stream,
                     predf, utf, args, b1, partb);
  hipLaunchKernelGGL(reduce_k, dim3((NTOK * ROLES) / 256), dim3(256), 0, stream,
                     partb, b2, out);
}